// Round 19
// baseline (152.376 us; speedup 1.0000x reference)
//
#include <hip/hip_runtime.h>
#include <hip/hip_bf16.h>
#include <math.h>

#define N_NODES 22
#define T_DIM   500
#define TP      512          // padded T
#define KHOP    3
#define KK      (KHOP*TP)    // 1536 padded K
#define MROWS   5632         // B*22
#define SLICE   (N_NODES*T_DIM)       // 11000 floats per (b,e) slice
#define SLICE4  (SLICE/4)             // 2750 v4f
#define NS      6                     // slices per bcast block (fallback path)
#define EFIX    40                    // expected emb_size (constant-divisor fast path)

typedef __bf16 v8bf __attribute__((ext_vector_type(8)));
typedef float  v4f  __attribute__((ext_vector_type(4)));

// ---------------- 1) fused prep: H-blocks (in-block softmax+A^2) + W-transpose blocks ----------------
__global__ __launch_bounds__(256) void prep_all(const float* __restrict__ x,
                                                const float* __restrict__ adj,
                                                const float* __restrict__ W,
                                                __hip_bfloat16* __restrict__ Hb,
                                                __hip_bfloat16* __restrict__ Wt, int B) {
    __shared__ __align__(16) char smem[26624];
    const int bid = blockIdx.x, tid = threadIdx.x;

    if (bid < 2*B) {
        float (*xs)[256] = (float(*)[256])smem;              // 22.0 KB
        float* As  = (float*)(smem + 22528);                 // 1.9 KB
        float* A2s = (float*)(smem + 24464);                 // 1.9 KB
        const int b = bid >> 1, t0 = (bid & 1) * 256;

        for (int idx = tid; idx < N_NODES*256; idx += 256) {
            int n = idx >> 8, t = idx & 255;
            int tg = t0 + t;
            xs[n][t] = (tg < T_DIM) ? x[((size_t)b*N_NODES + n)*T_DIM + tg] : 0.f;
        }
        if (tid < N_NODES) {
            float row[N_NODES];
            float m = -1e30f;
            for (int j = 0; j < N_NODES; ++j) { row[j] = adj[tid*N_NODES + j]; m = fmaxf(m, row[j]); }
            float s = 0.f;
            for (int j = 0; j < N_NODES; ++j) { row[j] = expf(row[j] - m); s += row[j]; }
            float inv = 1.f / s;
            for (int j = 0; j < N_NODES; ++j) As[tid*N_NODES + j] = row[j]*inv;
        }
        __syncthreads();
        for (int idx = tid; idx < N_NODES*N_NODES; idx += 256) {   // strided: 256 threads, 484 entries
            int n = idx / N_NODES, mm = idx - n*N_NODES;
            float s = 0.f;
            for (int k = 0; k < N_NODES; ++k) s += As[n*N_NODES + k] * As[k*N_NODES + mm];
            A2s[idx] = s;
        }
        __syncthreads();
        const int t = tid;
        for (int n = 0; n < N_NODES; ++n) {
            float h0 = xs[n][t];
            float h1 = 0.f, h2 = 0.f;
            for (int m = 0; m < N_NODES; ++m) {
                float xv = xs[m][t];
                h1 = fmaf(As[n*N_NODES + m],  xv, h1);
                h2 = fmaf(A2s[n*N_NODES + m], xv, h2);
            }
            size_t base = ((size_t)b*N_NODES + n)*KK + t0 + t;
            Hb[base]        = __float2bfloat16(h0);
            Hb[base + TP]   = __float2bfloat16(h1);
            Hb[base + 2*TP] = __float2bfloat16(h2);
        }
    } else {
        float (*tile)[65] = (float(*)[65])smem;              // 16.6 KB
        const int widx = bid - 2*B;                          // 0..191
        const int k = widx >> 6;
        const int rem = widx & 63;
        const int tb = (rem & 7) * 64, ob = (rem >> 3) * 64;
        const int tx = tid & 63, ty = tid >> 6;
#pragma unroll
        for (int r = ty; r < 64; r += 4) {
            int t = tb + r, o = ob + tx;
            tile[r][tx] = (t < T_DIM && o < T_DIM) ? W[(size_t)k*T_DIM*T_DIM + (size_t)t*T_DIM + o] : 0.f;
        }
        __syncthreads();
#pragma unroll
        for (int r = ty; r < 64; r += 4) {
            int o = ob + r, t = tb + tx;
            Wt[(size_t)o*KK + (size_t)k*TP + t] = __float2bfloat16(tile[tx][r]);
        }
    }
}

// ---------------- 2) MFMA GEMM, 2-phase dbuf LDS; XCD-local grid mapping (R15 known-good, reg-staged) ----------------
#define BM 64
#define BN 64
#define BK 64
#define NT (KK/BK)   // 24

__global__ __launch_bounds__(256) void gemm_compact(const __hip_bfloat16* __restrict__ Hb,
                                                    const __hip_bfloat16* __restrict__ Wt,
                                                    const float* __restrict__ bias,
                                                    float* __restrict__ out, int E) {
    __shared__ __hip_bfloat16 sA[2][BM*BK];   // 2 x 8 KB
    __shared__ __hip_bfloat16 sB[2][BN*BK];   // 2 x 8 KB
    const int tid  = threadIdx.x;
    const int bid  = blockIdx.x;
    const int bm   = bid % 88;
    const int bn   = bid / 88;             // 0..7  (XCD-local mapping)
    const int lane = tid & 63, wid = tid >> 6;
    const int wr = wid >> 1, wc = wid & 1; // wave -> 32-row x 32-col sub-tile

    const int row0_ = tid >> 3,           c0_ = tid & 7;          // rows 0..31
    const int row1_ = (tid + 256) >> 3,   c1_ = tid & 7;          // rows 32..63
    const int sOffA0 = (row0_*8 + (c0_ ^ (row0_ & 7)))*8;
    const int sOffA1 = (row1_*8 + (c1_ ^ (row1_ & 7)))*8;

    const size_t a_base = (size_t)(bm*BM) * KK;
    const size_t b_base = (size_t)(bn*BN) * KK;
    const __hip_bfloat16* gA0 = Hb + a_base + (size_t)row0_*KK + c0_*8;
    const __hip_bfloat16* gA1 = Hb + a_base + (size_t)row1_*KK + c1_*8;
    const __hip_bfloat16* gB0 = Wt + b_base + (size_t)row0_*KK + c0_*8;
    const __hip_bfloat16* gB1 = Wt + b_base + (size_t)row1_*KK + c1_*8;

    v4f acc[2][2];
#pragma unroll
    for (int m = 0; m < 2; ++m)
#pragma unroll
        for (int n = 0; n < 2; ++n) acc[m][n] = (v4f){0.f, 0.f, 0.f, 0.f};

    uint4 na0 = *(const uint4*)gA0;
    uint4 na1 = *(const uint4*)gA1;
    uint4 nb0 = *(const uint4*)gB0;
    uint4 nb1 = *(const uint4*)gB1;

    int cur = 0;
    for (int t = 0; t < NT; ++t) {
        *(uint4*)(sA[cur] + sOffA0) = na0;
        *(uint4*)(sA[cur] + sOffA1) = na1;
        *(uint4*)(sB[cur] + sOffA0) = nb0;
        *(uint4*)(sB[cur] + sOffA1) = nb1;
        __syncthreads();

        if (t + 1 < NT) {
            int k1 = (t + 1) * BK;
            na0 = *(const uint4*)(gA0 + k1);
            na1 = *(const uint4*)(gA1 + k1);
            nb0 = *(const uint4*)(gB0 + k1);
            nb1 = *(const uint4*)(gB1 + k1);
        }

#pragma unroll
        for (int ks = 0; ks < 2; ++ks) {
            v8bf af[2], bfr[2];
#pragma unroll
            for (int m = 0; m < 2; ++m) {
                int row = wr*32 + m*16 + (lane & 15);
                int c   = ks*4 + (lane >> 4);
                af[m] = *(const v8bf*)(sA[cur] + (row*8 + (c ^ (row & 7)))*8);
            }
#pragma unroll
            for (int n = 0; n < 2; ++n) {
                int row = wc*32 + n*16 + (lane & 15);
                int c   = ks*4 + (lane >> 4);
                bfr[n] = *(const v8bf*)(sB[cur] + (row*8 + (c ^ (row & 7)))*8);
            }
#pragma unroll
            for (int m = 0; m < 2; ++m)
#pragma unroll
                for (int n = 0; n < 2; ++n)
                    acc[m][n] = __builtin_amdgcn_mfma_f32_16x16x32_bf16(af[m], bfr[n], acc[m][n], 0, 0, 0);
        }
        cur ^= 1;
    }

    // epilogue: write ONLY e=0 slice. C/D layout col=lane&15, row=(lane>>4)*4+r
    const int row0 = bm*BM + wr*32;
    const int col0 = bn*BN + wc*32;
#pragma unroll
    for (int n = 0; n < 2; ++n) {
        int col = col0 + n*16 + (lane & 15);
        if (col >= T_DIM) continue;
        float bv = bias[col];
#pragma unroll
        for (int m = 0; m < 2; ++m) {
            int rowb = row0 + m*16 + ((lane >> 4) << 2);
#pragma unroll
            for (int r = 0; r < 4; ++r) {
                int row  = rowb + r;
                int bidx = row / N_NODES;
                int node = row - bidx*N_NODES;
                out[((size_t)bidx*E*N_NODES + node)*T_DIM + col] = acc[m][n][r] + bv;
            }
        }
    }
}

// ---------------- 3a) broadcast: device-wide monotonic grid-stride sweep (fill-kernel pattern) ----------------
// Linear v4f order over the (b, e>=1) region; all blocks advance together -> the device
// writes one sliding contiguous window, exactly like fillBufferAligned. Source reads hit
// the 44KB-hot e0 slice in L2. Constant divisors (E=EFIX) -> magic-mul, no div.
__global__ __launch_bounds__(256) void bcast_sweep(float* __restrict__ out, int B) {
    const unsigned PERB = (EFIX - 1) * SLICE4;          // 107250 v4f per b
    const unsigned total = (unsigned)B * PERB;          // 27.456M
    const unsigned stride = gridDim.x * 256u;
    for (unsigned i = blockIdx.x * 256u + threadIdx.x; i < total; i += stride) {
        unsigned b   = i / PERB;                        // constant divisor
        unsigned rem = i - b * PERB;
        unsigned s   = rem % (unsigned)SLICE4;          // constant divisor
        const size_t base = (size_t)b * EFIX * SLICE;
        v4f val = *(const v4f*)(out + base + (size_t)s * 4);
        *(v4f*)(out + base + SLICE + (size_t)rem * 4) = val;
    }
}

// ---------------- 3b) fallback (E != EFIX): R15 known-good NS=6 bcast ----------------
__global__ __launch_bounds__(256) void bcast3(float* __restrict__ out, int E) {
    const int b = blockIdx.x;
    const int g = blockIdx.y;
    const v4f* __restrict__ src = (const v4f*)(out + (size_t)b*E*SLICE);
    v4f vals[11];
#pragma unroll
    for (int c = 0; c < 11; ++c) {
        int i = (int)threadIdx.x + c*256;
        if (i < SLICE4) vals[c] = src[i];
    }
    const int e0 = 1 + g*NS;
#pragma unroll
    for (int e = 0; e < NS; ++e) {
        if (e0 + e >= E) break;
        v4f* __restrict__ dst = (v4f*)(out + ((size_t)b*E + e0 + e)*SLICE);
#pragma unroll
        for (int c = 0; c < 11; ++c) {
            int i = (int)threadIdx.x + c*256;
            if (i < SLICE4) dst[i] = vals[c];
        }
    }
}

extern "C" void kernel_launch(void* const* d_in, const int* in_sizes, int n_in,
                              void* d_out, int out_size, void* d_ws, size_t ws_size,
                              hipStream_t stream) {
    const float* x    = (const float*)d_in[0];
    const float* adj  = (const float*)d_in[1];
    const float* W    = (const float*)d_in[2];
    const float* bias = (const float*)d_in[3];
    const int B = in_sizes[0] / (N_NODES * T_DIM);            // 256
    const int E = out_size / (B * N_NODES * T_DIM);           // 40

    char* ws = (char*)d_ws;
    __hip_bfloat16* Wt = (__hip_bfloat16*)ws;                        // 1.5 MB
    __hip_bfloat16* Hb = (__hip_bfloat16*)(ws + (size_t)TP*KK*2);    // 16.5 MB
    float* out = (float*)d_out;

    prep_all<<<2*B + 192, 256, 0, stream>>>(x, adj, W, Hb, Wt, B);   // 704 blocks
    gemm_compact<<<704, 256, 0, stream>>>(Hb, Wt, bias, out, E);     // 1-D, XCD-local mapping
    if (E == EFIX) {
        bcast_sweep<<<2048, 256, 0, stream>>>(out, B);               // fill-pattern sweep
    } else if (E > 1) {
        dim3 bg(B, (E - 1 + NS - 1) / NS);
        bcast3<<<bg, 256, 0, stream>>>(out, E);
    }
}

// Round 20
// 133.129 us; speedup vs baseline: 1.1446x; 1.1446x over previous
//
#include <hip/hip_runtime.h>
#include <hip/hip_bf16.h>
#include <math.h>

#define N_NODES 22
#define T_DIM   500
#define TP      512          // padded T
#define KHOP    3
#define KK      (KHOP*TP)    // 1536 padded K
#define MROWS   5632         // B*22
#define SLICE   (N_NODES*T_DIM)       // 11000 floats per (b,e) slice
#define SLICE4  (SLICE/4)             // 2750 float4
#define NS      6                     // slices per bcast block

typedef __bf16 v8bf __attribute__((ext_vector_type(8)));
typedef float  v4f  __attribute__((ext_vector_type(4)));

// ---------------- 1) fused prep: H-blocks (in-block softmax+A^2) + W-transpose blocks ----------------
__global__ __launch_bounds__(256) void prep_all(const float* __restrict__ x,
                                                const float* __restrict__ adj,
                                                const float* __restrict__ W,
                                                __hip_bfloat16* __restrict__ Hb,
                                                __hip_bfloat16* __restrict__ Wt, int B) {
    __shared__ __align__(16) char smem[26624];
    const int bid = blockIdx.x, tid = threadIdx.x;

    if (bid < 2*B) {
        float (*xs)[256] = (float(*)[256])smem;              // 22.0 KB
        float* As  = (float*)(smem + 22528);                 // 1.9 KB
        float* A2s = (float*)(smem + 24464);                 // 1.9 KB
        const int b = bid >> 1, t0 = (bid & 1) * 256;

        for (int idx = tid; idx < N_NODES*256; idx += 256) {
            int n = idx >> 8, t = idx & 255;
            int tg = t0 + t;
            xs[n][t] = (tg < T_DIM) ? x[((size_t)b*N_NODES + n)*T_DIM + tg] : 0.f;
        }
        if (tid < N_NODES) {
            float row[N_NODES];
            float m = -1e30f;
            for (int j = 0; j < N_NODES; ++j) { row[j] = adj[tid*N_NODES + j]; m = fmaxf(m, row[j]); }
            float s = 0.f;
            for (int j = 0; j < N_NODES; ++j) { row[j] = expf(row[j] - m); s += row[j]; }
            float inv = 1.f / s;
            for (int j = 0; j < N_NODES; ++j) As[tid*N_NODES + j] = row[j]*inv;
        }
        __syncthreads();
        for (int idx = tid; idx < N_NODES*N_NODES; idx += 256) {   // strided: 256 threads, 484 entries
            int n = idx / N_NODES, mm = idx - n*N_NODES;
            float s = 0.f;
            for (int k = 0; k < N_NODES; ++k) s += As[n*N_NODES + k] * As[k*N_NODES + mm];
            A2s[idx] = s;
        }
        __syncthreads();
        const int t = tid;
        for (int n = 0; n < N_NODES; ++n) {
            float h0 = xs[n][t];
            float h1 = 0.f, h2 = 0.f;
            for (int m = 0; m < N_NODES; ++m) {
                float xv = xs[m][t];
                h1 = fmaf(As[n*N_NODES + m],  xv, h1);
                h2 = fmaf(A2s[n*N_NODES + m], xv, h2);
            }
            size_t base = ((size_t)b*N_NODES + n)*KK + t0 + t;
            Hb[base]        = __float2bfloat16(h0);
            Hb[base + TP]   = __float2bfloat16(h1);
            Hb[base + 2*TP] = __float2bfloat16(h2);
        }
    } else {
        float (*tile)[65] = (float(*)[65])smem;              // 16.6 KB
        const int widx = bid - 2*B;                          // 0..191
        const int k = widx >> 6;
        const int rem = widx & 63;
        const int tb = (rem & 7) * 64, ob = (rem >> 3) * 64;
        const int tx = tid & 63, ty = tid >> 6;
#pragma unroll
        for (int r = ty; r < 64; r += 4) {
            int t = tb + r, o = ob + tx;
            tile[r][tx] = (t < T_DIM && o < T_DIM) ? W[(size_t)k*T_DIM*T_DIM + (size_t)t*T_DIM + o] : 0.f;
        }
        __syncthreads();
#pragma unroll
        for (int r = ty; r < 64; r += 4) {
            int o = ob + r, t = tb + tx;
            Wt[(size_t)o*KK + (size_t)k*TP + t] = __float2bfloat16(tile[tx][r]);
        }
    }
}

// ---------------- 2) MFMA GEMM, 2-phase dbuf LDS; XCD-local grid mapping ----------------
// 1-D grid 704; bm = bid % 88, bn = bid / 88. Same-bm siblings share bid mod 8 ->
// same XCD -> A-panel L2 reuse (11 panels * 196KB + Wt 1.5MB < 4MB L2/XCD).
#define BM 64
#define BN 64
#define BK 64
#define NT (KK/BK)   // 24

__global__ __launch_bounds__(256) void gemm_compact(const __hip_bfloat16* __restrict__ Hb,
                                                    const __hip_bfloat16* __restrict__ Wt,
                                                    const float* __restrict__ bias,
                                                    float* __restrict__ out, int E) {
    __shared__ __hip_bfloat16 sA[2][BM*BK];   // 2 x 8 KB
    __shared__ __hip_bfloat16 sB[2][BN*BK];   // 2 x 8 KB
    const int tid  = threadIdx.x;
    const int bid  = blockIdx.x;
    const int bm   = bid % 88;
    const int bn   = bid / 88;             // 0..7
    const int lane = tid & 63, wid = tid >> 6;
    const int wr = wid >> 1, wc = wid & 1; // wave -> 32-row x 32-col sub-tile

    const int row0_ = tid >> 3,           c0_ = tid & 7;          // rows 0..31
    const int row1_ = (tid + 256) >> 3,   c1_ = tid & 7;          // rows 32..63
    const int sOffA0 = (row0_*8 + (c0_ ^ (row0_ & 7)))*8;
    const int sOffA1 = (row1_*8 + (c1_ ^ (row1_ & 7)))*8;

    const size_t a_base = (size_t)(bm*BM) * KK;
    const size_t b_base = (size_t)(bn*BN) * KK;
    const __hip_bfloat16* gA0 = Hb + a_base + (size_t)row0_*KK + c0_*8;
    const __hip_bfloat16* gA1 = Hb + a_base + (size_t)row1_*KK + c1_*8;
    const __hip_bfloat16* gB0 = Wt + b_base + (size_t)row0_*KK + c0_*8;
    const __hip_bfloat16* gB1 = Wt + b_base + (size_t)row1_*KK + c1_*8;

    v4f acc[2][2];
#pragma unroll
    for (int m = 0; m < 2; ++m)
#pragma unroll
        for (int n = 0; n < 2; ++n) acc[m][n] = (v4f){0.f, 0.f, 0.f, 0.f};

    uint4 na0 = *(const uint4*)gA0;
    uint4 na1 = *(const uint4*)gA1;
    uint4 nb0 = *(const uint4*)gB0;
    uint4 nb1 = *(const uint4*)gB1;

    int cur = 0;
    for (int t = 0; t < NT; ++t) {
        *(uint4*)(sA[cur] + sOffA0) = na0;
        *(uint4*)(sA[cur] + sOffA1) = na1;
        *(uint4*)(sB[cur] + sOffA0) = nb0;
        *(uint4*)(sB[cur] + sOffA1) = nb1;
        __syncthreads();

        if (t + 1 < NT) {
            int k1 = (t + 1) * BK;
            na0 = *(const uint4*)(gA0 + k1);
            na1 = *(const uint4*)(gA1 + k1);
            nb0 = *(const uint4*)(gB0 + k1);
            nb1 = *(const uint4*)(gB1 + k1);
        }

#pragma unroll
        for (int ks = 0; ks < 2; ++ks) {
            v8bf af[2], bfr[2];
#pragma unroll
            for (int m = 0; m < 2; ++m) {
                int row = wr*32 + m*16 + (lane & 15);
                int c   = ks*4 + (lane >> 4);
                af[m] = *(const v8bf*)(sA[cur] + (row*8 + (c ^ (row & 7)))*8);
            }
#pragma unroll
            for (int n = 0; n < 2; ++n) {
                int row = wc*32 + n*16 + (lane & 15);
                int c   = ks*4 + (lane >> 4);
                bfr[n] = *(const v8bf*)(sB[cur] + (row*8 + (c ^ (row & 7)))*8);
            }
#pragma unroll
            for (int m = 0; m < 2; ++m)
#pragma unroll
                for (int n = 0; n < 2; ++n)
                    acc[m][n] = __builtin_amdgcn_mfma_f32_16x16x32_bf16(af[m], bfr[n], acc[m][n], 0, 0, 0);
        }
        cur ^= 1;
    }

    // epilogue: write ONLY e=0 slice. C/D layout col=lane&15, row=(lane>>4)*4+r
    const int row0 = bm*BM + wr*32;
    const int col0 = bn*BN + wc*32;
#pragma unroll
    for (int n = 0; n < 2; ++n) {
        int col = col0 + n*16 + (lane & 15);
        if (col >= T_DIM) continue;
        float bv = bias[col];
#pragma unroll
        for (int m = 0; m < 2; ++m) {
            int rowb = row0 + m*16 + ((lane >> 4) << 2);
#pragma unroll
            for (int r = 0; r < 4; ++r) {
                int row  = rowb + r;
                int bidx = row / N_NODES;
                int node = row - bidx*N_NODES;
                out[((size_t)bidx*E*N_NODES + node)*T_DIM + col] = acc[m][n][r] + bv;
            }
        }
    }
}

// ---------------- 3) broadcast: reg-stage slice once, write NS consecutive e-slices ----------------
__global__ __launch_bounds__(256) void bcast3(float* __restrict__ out, int E) {
    const int b = blockIdx.x;
    const int g = blockIdx.y;
    const v4f* __restrict__ src = (const v4f*)(out + (size_t)b*E*SLICE);
    v4f vals[11];
#pragma unroll
    for (int c = 0; c < 11; ++c) {
        int i = (int)threadIdx.x + c*256;
        if (i < SLICE4) vals[c] = src[i];
    }
    const int e0 = 1 + g*NS;
#pragma unroll
    for (int e = 0; e < NS; ++e) {
        if (e0 + e >= E) break;
        v4f* __restrict__ dst = (v4f*)(out + ((size_t)b*E + e0 + e)*SLICE);
#pragma unroll
        for (int c = 0; c < 11; ++c) {
            int i = (int)threadIdx.x + c*256;
            if (i < SLICE4) dst[i] = vals[c];
        }
    }
}

extern "C" void kernel_launch(void* const* d_in, const int* in_sizes, int n_in,
                              void* d_out, int out_size, void* d_ws, size_t ws_size,
                              hipStream_t stream) {
    const float* x    = (const float*)d_in[0];
    const float* adj  = (const float*)d_in[1];
    const float* W    = (const float*)d_in[2];
    const float* bias = (const float*)d_in[3];
    const int B = in_sizes[0] / (N_NODES * T_DIM);            // 256
    const int E = out_size / (B * N_NODES * T_DIM);           // 40

    char* ws = (char*)d_ws;
    __hip_bfloat16* Wt = (__hip_bfloat16*)ws;                        // 1.5 MB
    __hip_bfloat16* Hb = (__hip_bfloat16*)(ws + (size_t)TP*KK*2);    // 16.5 MB
    float* out = (float*)d_out;

    prep_all<<<2*B + 192, 256, 0, stream>>>(x, adj, W, Hb, Wt, B);   // 704 blocks
    gemm_compact<<<704, 256, 0, stream>>>(Hb, Wt, bias, out, E);     // 1-D, XCD-local mapping
    if (E > 1) {
        dim3 bg(B, (E - 1 + NS - 1) / NS);   // (256, 7) = 1792 blocks
        bcast3<<<bg, 256, 0, stream>>>(out, E);
    }
}